// Round 6
// baseline (5683.566 us; speedup 1.0000x reference)
//
#include <hip/hip_runtime.h>

typedef __attribute__((ext_vector_type(4))) float f32x4;

// Problem constants
constexpr int B_  = 4;
constexpr int S_  = 2048;
constexpr int H_  = 16;
constexpr int DH_ = 64;
constexpr int D_  = 1024;

// ---------------------------------------------------------------------------
// Naive tiled f32 GEMM: C[m][n] = scale * sum_k A[m][k] * W[n][k]
// (y = x @ W.T, torch-Linear convention). 64x64 tile, 16 k-chunk,
// 256 threads, each owns a 4x4 micro-tile. All f32 in/out.
// CONTRACT (derived R0-R5): inputs f32, OUTPUT f32 (bf16-rounded values in
// f32 containers; writing bf16 to d_out was the R4/R5 failure mode).
// ---------------------------------------------------------------------------
__global__ __launch_bounds__(256)
void ngemm(const float* __restrict__ A, const float* __restrict__ W,
           float* __restrict__ out, float scale) {
  __shared__ float As[16][64];   // [k][m]
  __shared__ float Bs[16][64];   // [k][n]
  const int tid = threadIdx.x;
  const int tx  = tid & 15;      // n quad
  const int ty  = tid >> 4;      // m quad
  const int m0  = blockIdx.y * 64;
  const int n0  = blockIdx.x * 64;

  float acc[4][4] = {};

  const int srow = tid >> 2;         // staging row 0..63
  const int skc  = (tid & 3) * 4;    // staging k offset 0,4,8,12

  for (int k0 = 0; k0 < D_; k0 += 16) {
    __syncthreads();
    f32x4 av = *(const f32x4*)(A + (size_t)(m0 + srow) * D_ + k0 + skc);
    f32x4 bv = *(const f32x4*)(W + (size_t)(n0 + srow) * D_ + k0 + skc);
    #pragma unroll
    for (int i = 0; i < 4; ++i) {
      As[skc + i][srow] = av[i];
      Bs[skc + i][srow] = bv[i];
    }
    __syncthreads();
    #pragma unroll
    for (int kk = 0; kk < 16; ++kk) {
      f32x4 a = *(const f32x4*)(&As[kk][ty * 4]);
      f32x4 b = *(const f32x4*)(&Bs[kk][tx * 4]);
      #pragma unroll
      for (int i = 0; i < 4; ++i)
        #pragma unroll
        for (int j = 0; j < 4; ++j)
          acc[i][j] += a[i] * b[j];
    }
  }

  #pragma unroll
  for (int i = 0; i < 4; ++i)
    #pragma unroll
    for (int j = 0; j < 4; ++j) {
      int m = m0 + ty * 4 + i;
      int n = n0 + tx * 4 + j;
      out[(size_t)m * D_ + n] = acc[i][j] * scale;
    }
}

// ---------------------------------------------------------------------------
// Naive attention for ONE batch. Each thread owns ONE query row completely:
// q[64] and o[64] in registers, scalar online softmax. K/V tiles
// (64 keys x 64 dims f32) staged in LDS; inner reads are wave-broadcast.
// Q is pre-scaled by 1/sqrt(dh). All f32.
// ---------------------------------------------------------------------------
__global__ __launch_bounds__(256)
void nattn(const float* __restrict__ Qf,   // [S][D]
           const float* __restrict__ Kf,   // [S][D]
           const float* __restrict__ Vf,   // [S][D]
           const unsigned char* __restrict__ pmask, // [S] bytes, True = masked
           float* __restrict__ CTX) {      // [S][D]
  __shared__ float Ks[64][64];
  __shared__ float Vs[64][64];
  const int tid  = threadIdx.x;
  const int h    = blockIdx.y;
  const int q0   = blockIdx.x * 256;
  const int qrow = q0 + tid;

  float q[64], o[64];
  #pragma unroll
  for (int d = 0; d < 64; ++d) {
    q[d] = Qf[(size_t)qrow * D_ + h * 64 + d];
    o[d] = 0.f;
  }
  float m = -1e30f, l = 0.f;

  const int ntiles = (q0 + 256) / 64;   // causal: keys <= q0+255
  for (int kt = 0; kt < ntiles; ++kt) {
    const int k0 = kt * 64;
    __syncthreads();
    {
      int key = tid >> 2, dc = (tid & 3) * 16;
      #pragma unroll
      for (int u = 0; u < 4; ++u) {
        *(f32x4*)(&Ks[key][dc + u * 4]) =
            *(const f32x4*)(Kf + (size_t)(k0 + key) * D_ + h * 64 + dc + u * 4);
        *(f32x4*)(&Vs[key][dc + u * 4]) =
            *(const f32x4*)(Vf + (size_t)(k0 + key) * D_ + h * 64 + dc + u * 4);
      }
    }
    __syncthreads();

    #pragma unroll 1
    for (int kk = 0; kk < 64; ++kk) {
      int key = k0 + kk;
      float s = 0.f;
      #pragma unroll
      for (int d = 0; d < 64; ++d) s += q[d] * Ks[kk][d];
      bool valid = (key <= qrow) && (pmask[key] == 0);
      if (valid) {
        if (s > m) {                      // rescale only when max improves
          float corr = __expf(m - s);     // first valid key: exp(-1e30-s)=0
          l *= corr;
          #pragma unroll
          for (int d = 0; d < 64; ++d) o[d] *= corr;
          m = s;
        }
        float p = __expf(s - m);
        l += p;
        #pragma unroll
        for (int d = 0; d < 64; ++d) o[d] += p * Vs[kk][d];
      }
    }
  }

  float inv = 1.f / l;   // l >= 1 (key = qrow always valid)
  #pragma unroll
  for (int d = 0; d < 64; ++d)
    CTX[(size_t)qrow * D_ + h * 64 + d] = o[d] * inv;
}

// ---------------------------------------------------------------------------
// Per-batch schedule, all-f32 intermediates in natural [S][D] layout.
// ws peak: Qf | Kf | Vf | CTXf = 4 x 8 MB = 32 MB.
// ---------------------------------------------------------------------------
extern "C" void kernel_launch(void* const* d_in, const int* in_sizes, int n_in,
                              void* d_out, int out_size, void* d_ws, size_t ws_size,
                              hipStream_t stream) {
  const float* x  = (const float*)d_in[0];
  const float* Qw = (const float*)d_in[1];
  const float* Kw = (const float*)d_in[2];
  const float* Vw = (const float*)d_in[3];
  const float* Ow = (const float*)d_in[4];
  const unsigned char* pm = (const unsigned char*)d_in[5];
  float* out = (float*)d_out;                  // f32 output (R5 post-mortem)

  const size_t PB = (size_t)S_ * D_;   // elements per batch
  float* Qf   = (float*)d_ws;
  float* Kf   = Qf + PB;
  float* Vf   = Kf + PB;
  float* CTXf = Vf + PB;

  dim3 gg(D_ / 64, S_ / 64);           // (16, 32) per-batch GEMM grid
  dim3 ga(S_ / 256, H_);               // (8, 16) attention grid

  for (int b = 0; b < B_; ++b) {
    const float* xb = x + b * PB;
    ngemm<<<gg, 256, 0, stream>>>(xb, Qw, Qf, 0.125f);
    ngemm<<<gg, 256, 0, stream>>>(xb, Kw, Kf, 1.0f);
    ngemm<<<gg, 256, 0, stream>>>(xb, Vw, Vf, 1.0f);
    nattn<<<ga, 256, 0, stream>>>(Qf, Kf, Vf, pm + (size_t)b * S_, CTXf);
    ngemm<<<gg, 256, 0, stream>>>(CTXf, Ow, out + b * PB, 1.0f);
  }
}

// Round 7
// 921.851 us; speedup vs baseline: 6.1654x; 6.1654x over previous
//
#include <hip/hip_runtime.h>

typedef __attribute__((ext_vector_type(8))) short short8;
typedef __attribute__((ext_vector_type(4))) float f32x4;

#define MFMA_BF16_16x16x32(a,b,c) __builtin_amdgcn_mfma_f32_16x16x32_bf16((a),(b),(c),0,0,0)

// Problem constants
constexpr int B_  = 4;
constexpr int S_  = 2048;
constexpr int H_  = 16;
constexpr int DH_ = 64;
constexpr int D_  = 1024;

__device__ __forceinline__ unsigned short f2bf(float f) {
  union { float f; unsigned u; } v; v.f = f;
  unsigned u = v.u;
  u += 0x7fffu + ((u >> 16) & 1u);   // round-to-nearest-even
  return (unsigned short)(u >> 16);
}

__device__ __forceinline__ short8 cvt8(f32x4 a, f32x4 b) {
  short8 r;
  r[0] = (short)f2bf(a[0]); r[1] = (short)f2bf(a[1]);
  r[2] = (short)f2bf(a[2]); r[3] = (short)f2bf(a[3]);
  r[4] = (short)f2bf(b[0]); r[5] = (short)f2bf(b[1]);
  r[6] = (short)f2bf(b[2]); r[7] = (short)f2bf(b[3]);
  return r;
}

// ---------------------------------------------------------------------------
// GEMM: C[M,N] = A[M,K] * W[N,K]^T  (torch Linear, y = x @ W.T)
// A: f32 (A_F32) or bf16 (internal). W: always f32. Accum f32.
// OUT_F32: final projection writes f32 to d_out (harness contract, R5).
// EPI 0: out[m*D + n]
// EPI 1: out[((b*H+h)*S + s)*DH + d]   b = m>>11 (0 for per-batch launches)
// EPI 2: out[((b*H+h)*DH + d)*S + s]
// 128x128 tile, BK=32, 4 waves each owning a 64x64 sub-tile (4x4 MFMAs).
// MFMA fragment/epilogue layouts validated: R4 and the naive R5 pipeline
// produced bit-identical absmax under the old output encoding.
// ---------------------------------------------------------------------------
template <int EPI, bool A_F32, bool OUT_F32>
__global__ __launch_bounds__(256)
void gemm_bt(const void* __restrict__ Av,
             const float* __restrict__ W,
             void* __restrict__ outv,
             float scale) {
  constexpr int BM = 128, BN = 128, BK = 32;
  __shared__ __align__(16) short As[BM * BK];
  __shared__ __align__(16) short Bs[BN * BK];

  const int tid  = threadIdx.x;
  const int lane = tid & 63;
  const int w    = tid >> 6;          // wave 0..3
  const int quad = lane >> 4;         // 0..3
  const int l16  = lane & 15;
  const int wm   = (w >> 1) * 64;
  const int wn   = (w & 1) * 64;

  const int m0 = blockIdx.y * BM;
  const int n0 = blockIdx.x * BN;

  f32x4 acc[4][4];
  #pragma unroll
  for (int i = 0; i < 4; ++i)
    #pragma unroll
    for (int j = 0; j < 4; ++j)
      acc[i][j] = (f32x4){0.f, 0.f, 0.f, 0.f};

  for (int k0 = 0; k0 < D_; k0 += BK) {
    __syncthreads();   // protect previous-iteration LDS reads
    #pragma unroll
    for (int i = 0; i < 2; ++i) {
      int flat = i * 256 + tid;        // chunk id 0..511 (8 elems each)
      int row  = flat >> 2;            // 4 chunks (32 elems) per row
      int col  = (flat & 3) * 8;
      if (A_F32) {
        const float* Ap = (const float*)Av + (size_t)(m0 + row) * D_ + k0 + col;
        *(short8*)(&As[flat * 8]) = cvt8(*(const f32x4*)Ap, *(const f32x4*)(Ap + 4));
      } else {
        const unsigned short* Ap = (const unsigned short*)Av + (size_t)(m0 + row) * D_ + k0 + col;
        *(short8*)(&As[flat * 8]) = *(const short8*)Ap;
      }
      const float* Wp = W + (size_t)(n0 + row) * D_ + k0 + col;
      *(short8*)(&Bs[flat * 8]) = cvt8(*(const f32x4*)Wp, *(const f32x4*)(Wp + 4));
    }
    __syncthreads();

    short8 af[4], bf[4];
    #pragma unroll
    for (int i = 0; i < 4; ++i)
      af[i] = *(const short8*)(&As[(wm + i * 16 + l16) * BK + quad * 8]);
    #pragma unroll
    for (int j = 0; j < 4; ++j)
      bf[j] = *(const short8*)(&Bs[(wn + j * 16 + l16) * BK + quad * 8]);
    #pragma unroll
    for (int i = 0; i < 4; ++i)
      #pragma unroll
      for (int j = 0; j < 4; ++j)
        acc[i][j] = MFMA_BF16_16x16x32(af[i], bf[j], acc[i][j]);
  }

  // epilogue — C/D layout: col = lane&15, row = quad*4 + reg  (m89/m91)
  #pragma unroll
  for (int i = 0; i < 4; ++i) {
    #pragma unroll
    for (int j = 0; j < 4; ++j) {
      #pragma unroll
      for (int r = 0; r < 4; ++r) {
        int m = m0 + wm + i * 16 + quad * 4 + r;
        int n = n0 + wn + j * 16 + l16;
        float v = acc[i][j][r] * scale;
        if (EPI == 0) {
          if (OUT_F32) ((float*)outv)[(size_t)m * D_ + n] = v;
          else ((unsigned short*)outv)[(size_t)m * D_ + n] = f2bf(v);
        } else {
          int b = m >> 11, s = m & (S_ - 1);
          int h = n >> 6,  d = n & (DH_ - 1);
          if (EPI == 1)
            ((unsigned short*)outv)[((size_t)(b * H_ + h) * S_ + s) * DH_ + d] = f2bf(v);
          else
            ((unsigned short*)outv)[((size_t)(b * H_ + h) * DH_ + d) * S_ + s] = f2bf(v);
        }
      }
    }
  }
}

// ---------------------------------------------------------------------------
// MFMA flash attention for ONE batch: grid = (S/64 q-tiles, H heads).
// Block = 64 query rows; 4 waves x 16 rows; K-tile = 64 keys in LDS
// ([key][dim]); V from transposed [h,dh,S] buffer ([dim][key] in LDS).
// Online softmax over quad-spread rows; P via wave-private LDS round-trip.
// ---------------------------------------------------------------------------
__global__ __launch_bounds__(256)
void attn(const unsigned short* __restrict__ Q,    // [H,S,DH], pre-scaled 1/8
          const unsigned short* __restrict__ K,    // [H,S,DH]
          const unsigned short* __restrict__ VT,   // [H,DH,S]
          const unsigned char* __restrict__ pmask, // [S] bytes (True = masked)
          unsigned short* __restrict__ CTX) {      // [S, H*DH]
  __shared__ __align__(16) short Ks[64 * 64];
  __shared__ __align__(16) short Vs[64 * 64];
  __shared__ __align__(16) short Ps[4 * 16 * 64];

  const int tid  = threadIdx.x;
  const int lane = tid & 63;
  const int w    = tid >> 6;
  const int quad = lane >> 4;
  const int l16  = lane & 15;

  const int h  = blockIdx.y;
  const int q0 = blockIdx.x * 64;
  const int qw = q0 + w * 16;

  const unsigned short* Qh = Q  + (size_t)h * S_ * DH_;
  const unsigned short* Kh = K  + (size_t)h * S_ * DH_;
  const unsigned short* Vh = VT + (size_t)h * DH_ * S_;
  short* Pw = &Ps[w * 16 * 64];

  // Q fragments, K-loop invariant: A-layout m=lane&15, k=quad*8+j (m120)
  short8 qf0 = *(const short8*)(Qh + (size_t)(qw + l16) * DH_ + quad * 8);
  short8 qf1 = *(const short8*)(Qh + (size_t)(qw + l16) * DH_ + 32 + quad * 8);

  f32x4 acc[4];
  #pragma unroll
  for (int t = 0; t < 4; ++t) acc[t] = (f32x4){0.f, 0.f, 0.f, 0.f};
  float mrow[4], lrow[4];
  #pragma unroll
  for (int r = 0; r < 4; ++r) { mrow[r] = -1e30f; lrow[r] = 0.f; }

  const int ntiles = blockIdx.x + 1;   // causal: keys <= q0+63
  for (int kt = 0; kt < ntiles; ++kt) {
    const int k0 = kt * 64;
    __syncthreads();
    #pragma unroll
    for (int i = 0; i < 2; ++i) {
      int flat = i * 256 + tid;        // chunk 0..511 (8 elems each)
      int r = flat >> 3;               // row 0..63
      int c = (flat & 7) * 8;
      *(short8*)(&Ks[r * 64 + c]) = *(const short8*)(Kh + (size_t)(k0 + r) * DH_ + c);
      *(short8*)(&Vs[r * 64 + c]) = *(const short8*)(Vh + (size_t)r * S_ + k0 + c);
    }
    __syncthreads();

    // scores: 16 q-rows x 64 keys
    f32x4 sc[4];
    #pragma unroll
    for (int t = 0; t < 4; ++t) {
      short8 kb0 = *(const short8*)(&Ks[(t * 16 + l16) * 64 + quad * 8]);
      short8 kb1 = *(const short8*)(&Ks[(t * 16 + l16) * 64 + 32 + quad * 8]);
      f32x4 z = (f32x4){0.f, 0.f, 0.f, 0.f};
      z = MFMA_BF16_16x16x32(qf0, kb0, z);
      z = MFMA_BF16_16x16x32(qf1, kb1, z);
      sc[t] = z;
    }

    // causal + padding mask (True = masked -> -1e30)
    #pragma unroll
    for (int t = 0; t < 4; ++t) {
      int key = k0 + t * 16 + l16;
      bool pad = pmask[key] != 0;
      #pragma unroll
      for (int r = 0; r < 4; ++r) {
        int qrow = qw + quad * 4 + r;
        if (pad || key > qrow) sc[t][r] = -1e30f;
      }
    }

    // online softmax per row (row = qw + quad*4 + r)
    #pragma unroll
    for (int r = 0; r < 4; ++r) {
      float rm = fmaxf(fmaxf(sc[0][r], sc[1][r]), fmaxf(sc[2][r], sc[3][r]));
      #pragma unroll
      for (int off = 8; off; off >>= 1) rm = fmaxf(rm, __shfl_xor(rm, off, 16));
      float mnew = fmaxf(mrow[r], rm);
      float al = __expf(mrow[r] - mnew);
      float rs = 0.f;
      #pragma unroll
      for (int t = 0; t < 4; ++t) {
        float p = __expf(sc[t][r] - mnew);
        sc[t][r] = p;
        rs += p;
      }
      #pragma unroll
      for (int off = 8; off; off >>= 1) rs += __shfl_xor(rs, off, 16);
      lrow[r] = lrow[r] * al + rs;
      mrow[r] = mnew;
      #pragma unroll
      for (int t = 0; t < 4; ++t) acc[t][r] *= al;
    }

    // P (C-layout) -> LDS [16 rows][64 keys]; barrier before vector re-read
    #pragma unroll
    for (int t = 0; t < 4; ++t)
      #pragma unroll
      for (int r = 0; r < 4; ++r)
        Pw[(quad * 4 + r) * 64 + t * 16 + l16] = (short)f2bf(sc[t][r]);
    __syncthreads();

    // O += P * V
    #pragma unroll
    for (int ks = 0; ks < 2; ++ks) {
      short8 pa = *(const short8*)(&Pw[l16 * 64 + ks * 32 + quad * 8]);
      #pragma unroll
      for (int t = 0; t < 4; ++t) {
        short8 vb = *(const short8*)(&Vs[(t * 16 + l16) * 64 + ks * 32 + quad * 8]);
        acc[t] = MFMA_BF16_16x16x32(pa, vb, acc[t]);
      }
    }
  }

  // epilogue: ctx[q, h*64+d] = acc / l
  #pragma unroll
  for (int r = 0; r < 4; ++r) {
    int qrow = qw + quad * 4 + r;
    float inv = 1.0f / lrow[r];
    #pragma unroll
    for (int t = 0; t < 4; ++t) {
      int d = t * 16 + l16;
      CTX[(size_t)qrow * D_ + h * DH_ + d] = f2bf(acc[t][r] * inv);
    }
  }
}

// ---------------------------------------------------------------------------
// Contract: inputs f32 (bf16-rounded values), OUTPUT f32.
// ws (28 MB peak, <= 32 MB proven in R5):
//   Qall bf16 [B][H,S,DH] (16 MB) | Kb bf16 (4 MB) | VTb (4 MB) | CTXb (4 MB)
// ---------------------------------------------------------------------------
extern "C" void kernel_launch(void* const* d_in, const int* in_sizes, int n_in,
                              void* d_out, int out_size, void* d_ws, size_t ws_size,
                              hipStream_t stream) {
  const float* x  = (const float*)d_in[0];
  const float* Qw = (const float*)d_in[1];
  const float* Kw = (const float*)d_in[2];
  const float* Vw = (const float*)d_in[3];
  const float* Ow = (const float*)d_in[4];
  const unsigned char* pm = (const unsigned char*)d_in[5];
  float* out = (float*)d_out;

  const size_t PB = (size_t)S_ * D_;   // elements per batch (2M)
  unsigned short* Qall = (unsigned short*)d_ws;             // 16 MB
  unsigned short* Kb   = Qall + (size_t)B_ * PB;            //  4 MB
  unsigned short* VTb  = Kb + PB;                           //  4 MB
  unsigned short* CTXb = VTb + PB;                          //  4 MB

  dim3 gfull(D_ / 128, B_ * S_ / 128); // (8, 64) full-M grid
  dim3 gb(D_ / 128, S_ / 128);         // (8, 16) per-batch grid

  // Q for all batches, pre-scaled by 1/sqrt(dh)=0.125, [b][h][s][dh]
  gemm_bt<1, true, false><<<gfull, 256, 0, stream>>>(x, Qw, Qall, 0.125f);

  for (int b = 0; b < B_; ++b) {
    const float* xb = x + b * PB;
    gemm_bt<1, true, false><<<gb, 256, 0, stream>>>(xb, Kw, Kb,  1.0f);
    gemm_bt<2, true, false><<<gb, 256, 0, stream>>>(xb, Vw, VTb, 1.0f);
    attn<<<dim3(S_ / 64, H_), 256, 0, stream>>>(Qall + b * PB, Kb, VTb,
                                                pm + (size_t)b * S_, CTXb);
    gemm_bt<0, false, true><<<gb, 256, 0, stream>>>(CTXb, Ow, out + b * PB, 1.0f);
  }
}

// Round 8
// 527.598 us; speedup vs baseline: 10.7725x; 1.7473x over previous
//
#include <hip/hip_runtime.h>

typedef __attribute__((ext_vector_type(8))) short short8;
typedef __attribute__((ext_vector_type(4))) float f32x4;

#define MFMA_BF16_16x16x32(a,b,c) __builtin_amdgcn_mfma_f32_16x16x32_bf16((a),(b),(c),0,0,0)

// Problem constants
constexpr int B_  = 4;
constexpr int S_  = 2048;
constexpr int H_  = 16;
constexpr int DH_ = 64;
constexpr int D_  = 1024;
constexpr int M_  = B_ * S_;

__device__ __forceinline__ unsigned short f2bf(float f) {
  union { float f; unsigned u; } v; v.f = f;
  unsigned u = v.u;
  u += 0x7fffu + ((u >> 16) & 1u);   // round-to-nearest-even
  return (unsigned short)(u >> 16);
}

__device__ __forceinline__ short8 cvt8(f32x4 a, f32x4 b) {
  short8 r;
  r[0] = (short)f2bf(a[0]); r[1] = (short)f2bf(a[1]);
  r[2] = (short)f2bf(a[2]); r[3] = (short)f2bf(a[3]);
  r[4] = (short)f2bf(b[0]); r[5] = (short)f2bf(b[1]);
  r[6] = (short)f2bf(b[2]); r[7] = (short)f2bf(b[3]);
  return r;
}

// ---------------------------------------------------------------------------
// GEMM: C[M,N] = A[M,K] * W[N,K]^T  (torch Linear). A: f32 or bf16; W: f32.
// EPI 0: out[m*D + n]          EPI 1: Q/K head-major [b][h][s][dh]
// EPI 2: V transposed [b][h][dh][s]       (b = m>>11, full-M launches)
// 128x128 tile, BK=32, LDS rows padded to 40 shorts (16-way -> 2-way
// bank conflicts on ds_read_b128 fragment loads).
// ---------------------------------------------------------------------------
template <int EPI, bool A_F32, bool OUT_F32>
__global__ __launch_bounds__(256)
void gemm_bt(const void* __restrict__ Av,
             const float* __restrict__ W,
             void* __restrict__ outv,
             float scale) {
  constexpr int BM = 128, BN = 128, BK = 32, LDK = 40;
  __shared__ __align__(16) short As[BM * LDK];
  __shared__ __align__(16) short Bs[BN * LDK];

  const int tid  = threadIdx.x;
  const int lane = tid & 63;
  const int w    = tid >> 6;
  const int quad = lane >> 4;
  const int l16  = lane & 15;
  const int wm   = (w >> 1) * 64;
  const int wn   = (w & 1) * 64;

  const int m0 = blockIdx.y * BM;
  const int n0 = blockIdx.x * BN;

  f32x4 acc[4][4];
  #pragma unroll
  for (int i = 0; i < 4; ++i)
    #pragma unroll
    for (int j = 0; j < 4; ++j)
      acc[i][j] = (f32x4){0.f, 0.f, 0.f, 0.f};

  for (int k0 = 0; k0 < D_; k0 += BK) {
    __syncthreads();
    #pragma unroll
    for (int i = 0; i < 2; ++i) {
      int flat = i * 256 + tid;        // chunk 0..511 (8 elems each)
      int row  = flat >> 2;
      int col  = (flat & 3) * 8;
      if (A_F32) {
        const float* Ap = (const float*)Av + (size_t)(m0 + row) * D_ + k0 + col;
        *(short8*)(&As[row * LDK + col]) = cvt8(*(const f32x4*)Ap, *(const f32x4*)(Ap + 4));
      } else {
        const unsigned short* Ap = (const unsigned short*)Av + (size_t)(m0 + row) * D_ + k0 + col;
        *(short8*)(&As[row * LDK + col]) = *(const short8*)Ap;
      }
      const float* Wp = W + (size_t)(n0 + row) * D_ + k0 + col;
      *(short8*)(&Bs[row * LDK + col]) = cvt8(*(const f32x4*)Wp, *(const f32x4*)(Wp + 4));
    }
    __syncthreads();

    short8 af[4], bf[4];
    #pragma unroll
    for (int i = 0; i < 4; ++i)
      af[i] = *(const short8*)(&As[(wm + i * 16 + l16) * LDK + quad * 8]);
    #pragma unroll
    for (int j = 0; j < 4; ++j)
      bf[j] = *(const short8*)(&Bs[(wn + j * 16 + l16) * LDK + quad * 8]);
    #pragma unroll
    for (int i = 0; i < 4; ++i)
      #pragma unroll
      for (int j = 0; j < 4; ++j)
        acc[i][j] = MFMA_BF16_16x16x32(af[i], bf[j], acc[i][j]);
  }

  // epilogue — C/D layout: col = lane&15, row = quad*4 + reg (m89/m91)
  #pragma unroll
  for (int i = 0; i < 4; ++i) {
    #pragma unroll
    for (int j = 0; j < 4; ++j) {
      #pragma unroll
      for (int r = 0; r < 4; ++r) {
        int m = m0 + wm + i * 16 + quad * 4 + r;
        int n = n0 + wn + j * 16 + l16;
        float v = acc[i][j][r] * scale;
        if (EPI == 0) {
          if (OUT_F32) ((float*)outv)[(size_t)m * D_ + n] = v;
          else ((unsigned short*)outv)[(size_t)m * D_ + n] = f2bf(v);
        } else {
          int b = m >> 11, s = m & (S_ - 1);
          int h = n >> 6,  d = n & (DH_ - 1);
          if (EPI == 1)
            ((unsigned short*)outv)[((size_t)(b * H_ + h) * S_ + s) * DH_ + d] = f2bf(v);
          else
            ((unsigned short*)outv)[((size_t)(b * H_ + h) * DH_ + d) * S_ + s] = f2bf(v);
        }
      }
    }
  }
}

// ---------------------------------------------------------------------------
// MFMA flash attention, single dispatch: grid = (S/128, H, B).
// Block = 128 q-rows; wave w owns 32 rows (two 16-row subtiles).
// K-tile = 64 keys. LDS rows padded 64->72 shorts (2-way conflicts only).
// Waves whose 32 rows are entirely left of the tile skip compute (causal).
// ---------------------------------------------------------------------------
__global__ __launch_bounds__(256)
void attn(const unsigned short* __restrict__ Q,    // [B][H,S,DH], pre-scaled 1/8
          const unsigned short* __restrict__ K,    // [B][H,S,DH]
          const unsigned short* __restrict__ VT,   // [B][H,DH,S]
          const unsigned char* __restrict__ pmask, // [B][S] (True = masked)
          unsigned short* __restrict__ CTX) {      // [B][S, H*DH]
  constexpr int LDP = 72;
  __shared__ __align__(16) short Ks[64 * LDP];
  __shared__ __align__(16) short Vs[64 * LDP];
  __shared__ __align__(16) short Ps[4 * 32 * LDP];

  const int tid  = threadIdx.x;
  const int lane = tid & 63;
  const int w    = tid >> 6;
  const int quad = lane >> 4;
  const int l16  = lane & 15;

  const int b  = blockIdx.z;
  const int h  = blockIdx.y;
  const int q0 = blockIdx.x * 128;
  const int qw = q0 + w * 32;          // this wave's 32 query rows

  const unsigned short* Qh = Q  + ((size_t)b * H_ + h) * S_ * DH_;
  const unsigned short* Kh = K  + ((size_t)b * H_ + h) * S_ * DH_;
  const unsigned short* Vh = VT + ((size_t)b * H_ + h) * DH_ * S_;
  const unsigned char* pmb = pmask + (size_t)b * S_;
  unsigned short* CTXb = CTX + (size_t)b * S_ * D_;
  short* Pw = &Ps[w * 32 * LDP];

  // Q fragments (A-layout m=lane&15, k=quad*8+j), K-loop invariant
  short8 qf[2][2];
  #pragma unroll
  for (int i = 0; i < 2; ++i)
    #pragma unroll
    for (int c = 0; c < 2; ++c)
      qf[i][c] = *(const short8*)(Qh + (size_t)(qw + i * 16 + l16) * DH_ + c * 32 + quad * 8);

  f32x4 acc[2][4];
  float mrow[2][4], lrow[2][4];
  #pragma unroll
  for (int i = 0; i < 2; ++i)
    #pragma unroll
    for (int t = 0; t < 4; ++t) acc[i][t] = (f32x4){0.f, 0.f, 0.f, 0.f};
  #pragma unroll
  for (int i = 0; i < 2; ++i)
    #pragma unroll
    for (int r = 0; r < 4; ++r) { mrow[i][r] = -1e30f; lrow[i][r] = 0.f; }

  const int ntiles = blockIdx.x * 2 + 2;   // keys <= q0+127
  for (int kt = 0; kt < ntiles; ++kt) {
    const int k0 = kt * 64;
    __syncthreads();   // prior PV reads of Ks/Vs done before restage
    #pragma unroll
    for (int i = 0; i < 2; ++i) {
      int flat = i * 256 + tid;        // chunk 0..511 (8 elems)
      int r = flat >> 3;               // key/dim row 0..63
      int c = (flat & 7) * 8;
      *(short8*)(&Ks[r * LDP + c]) = *(const short8*)(Kh + (size_t)(k0 + r) * DH_ + c);
      *(short8*)(&Vs[r * LDP + c]) = *(const short8*)(Vh + (size_t)r * S_ + k0 + c);
    }
    __syncthreads();

    const bool active = (k0 <= qw + 31);   // else tile fully causal-masked
    if (active) {
      f32x4 sc[2][4];
      #pragma unroll
      for (int t = 0; t < 4; ++t) {
        short8 kb0 = *(const short8*)(&Ks[(t * 16 + l16) * LDP + quad * 8]);
        short8 kb1 = *(const short8*)(&Ks[(t * 16 + l16) * LDP + 32 + quad * 8]);
        #pragma unroll
        for (int i = 0; i < 2; ++i) {
          f32x4 z = (f32x4){0.f, 0.f, 0.f, 0.f};
          z = MFMA_BF16_16x16x32(qf[i][0], kb0, z);
          sc[i][t] = MFMA_BF16_16x16x32(qf[i][1], kb1, z);
        }
      }

      // causal + padding mask
      #pragma unroll
      for (int t = 0; t < 4; ++t) {
        int key = k0 + t * 16 + l16;
        bool pad = pmb[key] != 0;
        #pragma unroll
        for (int i = 0; i < 2; ++i)
          #pragma unroll
          for (int r = 0; r < 4; ++r) {
            int qrow = qw + i * 16 + quad * 4 + r;
            if (pad || key > qrow) sc[i][t][r] = -1e30f;
          }
      }

      // online softmax per row (rows spread over the 16 l16 lanes)
      #pragma unroll
      for (int i = 0; i < 2; ++i)
        #pragma unroll
        for (int r = 0; r < 4; ++r) {
          float rm = fmaxf(fmaxf(sc[i][0][r], sc[i][1][r]), fmaxf(sc[i][2][r], sc[i][3][r]));
          #pragma unroll
          for (int off = 8; off; off >>= 1) rm = fmaxf(rm, __shfl_xor(rm, off, 16));
          float mnew = fmaxf(mrow[i][r], rm);
          float al = __expf(mrow[i][r] - mnew);
          float rs = 0.f;
          #pragma unroll
          for (int t = 0; t < 4; ++t) {
            float p = __expf(sc[i][t][r] - mnew);
            sc[i][t][r] = p;
            rs += p;
          }
          #pragma unroll
          for (int off = 8; off; off >>= 1) rs += __shfl_xor(rs, off, 16);
          lrow[i][r] = lrow[i][r] * al + rs;
          mrow[i][r] = mnew;
          #pragma unroll
          for (int t = 0; t < 4; ++t) acc[i][t][r] *= al;
        }

      // P (C-layout) -> wave-private LDS [32 rows][64 keys]
      #pragma unroll
      for (int i = 0; i < 2; ++i)
        #pragma unroll
        for (int t = 0; t < 4; ++t)
          #pragma unroll
          for (int r = 0; r < 4; ++r)
            Pw[(i * 16 + quad * 4 + r) * LDP + t * 16 + l16] = (short)f2bf(sc[i][t][r]);
    }
    __syncthreads();   // order P-store vs vector re-read (R4-validated)

    if (active) {
      #pragma unroll
      for (int ks = 0; ks < 2; ++ks) {
        short8 pa0 = *(const short8*)(&Pw[l16 * LDP + ks * 32 + quad * 8]);
        short8 pa1 = *(const short8*)(&Pw[(16 + l16) * LDP + ks * 32 + quad * 8]);
        #pragma unroll
        for (int t = 0; t < 4; ++t) {
          short8 vb = *(const short8*)(&Vs[(t * 16 + l16) * LDP + ks * 32 + quad * 8]);
          acc[0][t] = MFMA_BF16_16x16x32(pa0, vb, acc[0][t]);
          acc[1][t] = MFMA_BF16_16x16x32(pa1, vb, acc[1][t]);
        }
      }
    }
  }

  // epilogue: ctx[q, h*64+d] = acc / l
  #pragma unroll
  for (int i = 0; i < 2; ++i)
    #pragma unroll
    for (int r = 0; r < 4; ++r) {
      int qrow = qw + i * 16 + quad * 4 + r;
      float inv = 1.0f / lrow[i][r];
      #pragma unroll
      for (int t = 0; t < 4; ++t)
        CTXb[(size_t)qrow * D_ + h * DH_ + t * 16 + l16] = f2bf(acc[i][t][r] * inv);
    }
}

// ---------------------------------------------------------------------------
// Contract: inputs f32, OUTPUT f32. ws usage exactly 32 MB (proven R5).
// d_out (33.5 MB) doubles as staging: Q bf16 [0,16M), CTX bf16 [16M,32M).
// Schedule: Q|K|VT full-M GEMMs -> attn (one dispatch) -> d2d CTX->ws ->
// final full-M GEMM (reads ws, writes f32 d_out; no intra-kernel hazard).
// ---------------------------------------------------------------------------
extern "C" void kernel_launch(void* const* d_in, const int* in_sizes, int n_in,
                              void* d_out, int out_size, void* d_ws, size_t ws_size,
                              hipStream_t stream) {
  const float* x  = (const float*)d_in[0];
  const float* Qw = (const float*)d_in[1];
  const float* Kw = (const float*)d_in[2];
  const float* Vw = (const float*)d_in[3];
  const float* Ow = (const float*)d_in[4];
  const unsigned char* pm = (const unsigned char*)d_in[5];

  const size_t NE = (size_t)M_ * D_;               // 8.4M elements
  unsigned short* Qall  = (unsigned short*)d_out;            // 16 MB bf16
  unsigned short* CTXa  = (unsigned short*)d_out + NE;       // 16 MB bf16
  unsigned short* Kall  = (unsigned short*)d_ws;             // 16 MB
  unsigned short* VTall = (unsigned short*)d_ws + NE;        // 16 MB

  dim3 gfull(D_ / 128, M_ / 128);   // (8, 64) = 512 blocks

  gemm_bt<1, true, false><<<gfull, 256, 0, stream>>>(x, Qw, Qall, 0.125f);
  gemm_bt<1, true, false><<<gfull, 256, 0, stream>>>(x, Kw, Kall, 1.0f);
  gemm_bt<2, true, false><<<gfull, 256, 0, stream>>>(x, Vw, VTall, 1.0f);

  attn<<<dim3(S_ / 128, H_, B_), 256, 0, stream>>>(Qall, Kall, VTall, pm, CTXa);

  // CTX -> ws (K region dead); frees d_out for the hazard-free final GEMM
  hipMemcpyAsync(d_ws, (const void*)CTXa, NE * sizeof(unsigned short),
                 hipMemcpyDeviceToDevice, stream);

  gemm_bt<0, false, true><<<gfull, 256, 0, stream>>>((unsigned short*)d_ws, Ow,
                                                     d_out, 1.0f);
}

// Round 9
// 506.969 us; speedup vs baseline: 11.2109x; 1.0407x over previous
//
#include <hip/hip_runtime.h>
#include <hip/hip_bf16.h>

typedef __attribute__((ext_vector_type(8))) short short8;
typedef __attribute__((ext_vector_type(4))) float f32x4;

#define MFMA_BF16_16x16x32(a,b,c) __builtin_amdgcn_mfma_f32_16x16x32_bf16((a),(b),(c),0,0,0)

// Problem constants
constexpr int B_  = 4;
constexpr int S_  = 2048;
constexpr int H_  = 16;
constexpr int DH_ = 64;
constexpr int D_  = 1024;
constexpr int M_  = B_ * S_;

__device__ __forceinline__ unsigned short f2bf(float f) {
  union { float f; unsigned u; } v; v.f = f;
  unsigned u = v.u;
  u += 0x7fffu + ((u >> 16) & 1u);   // RNE
  return (unsigned short)(u >> 16);
}

// Packed f32x8 -> bf16x8 via v_cvt_pk_bf16_f32 (1 inst / 2 elems, vs ~4 VALU
// per elem for the manual shift-round; staging was VALU-bound in R8 profile).
__device__ __forceinline__ short8 cvt8(f32x4 a, f32x4 b) {
  union { __hip_bfloat162 h[4]; short8 s; } u;
  u.h[0] = __float22bfloat162_rn(make_float2(a[0], a[1]));
  u.h[1] = __float22bfloat162_rn(make_float2(a[2], a[3]));
  u.h[2] = __float22bfloat162_rn(make_float2(b[0], b[1]));
  u.h[3] = __float22bfloat162_rn(make_float2(b[2], b[3]));
  return u.s;
}

// ---------------------------------------------------------------------------
// Fused QKV projection: one dispatch, gridDim.x = 24 n-blocks.
//   n-blocks 0-7: Q = x@Qw^T * 0.125 -> [b][h][s][dh]
//   n-blocks 8-15: K -> [b][h][s][dh];  16-23: V -> [b][h][dh][s]
// 128x128 tile, BK=32, LDS rows padded to 40 shorts (2-way conflicts only).
// ---------------------------------------------------------------------------
__global__ __launch_bounds__(256)
void gemm_qkv(const float* __restrict__ x,
              const float* __restrict__ Qw, const float* __restrict__ Kw,
              const float* __restrict__ Vw,
              unsigned short* __restrict__ Qo, unsigned short* __restrict__ Ko,
              unsigned short* __restrict__ VTo) {
  constexpr int BM = 128, BK = 32, LDK = 40;
  __shared__ __align__(16) short As[BM * LDK];
  __shared__ __align__(16) short Bs[BM * LDK];

  const int nb = blockIdx.x;           // 0..23, wave-uniform selects
  const float* W;
  unsigned short* out;
  float scale = 1.0f;
  int epi;
  if (nb < 8)       { W = Qw; out = Qo;  scale = 0.125f; epi = 1; }
  else if (nb < 16) { W = Kw; out = Ko;  epi = 1; }
  else              { W = Vw; out = VTo; epi = 2; }

  const int tid  = threadIdx.x;
  const int lane = tid & 63;
  const int w    = tid >> 6;
  const int quad = lane >> 4;
  const int l16  = lane & 15;
  const int wm   = (w >> 1) * 64;
  const int wn   = (w & 1) * 64;

  const int m0 = blockIdx.y * BM;
  const int n0 = (nb & 7) * 128;

  f32x4 acc[4][4];
  #pragma unroll
  for (int i = 0; i < 4; ++i)
    #pragma unroll
    for (int j = 0; j < 4; ++j)
      acc[i][j] = (f32x4){0.f, 0.f, 0.f, 0.f};

  for (int k0 = 0; k0 < D_; k0 += BK) {
    __syncthreads();
    #pragma unroll
    for (int i = 0; i < 2; ++i) {
      int flat = i * 256 + tid;
      int row  = flat >> 2;
      int col  = (flat & 3) * 8;
      const float* Ap = x + (size_t)(m0 + row) * D_ + k0 + col;
      *(short8*)(&As[row * LDK + col]) = cvt8(*(const f32x4*)Ap, *(const f32x4*)(Ap + 4));
      const float* Wp = W + (size_t)(n0 + row) * D_ + k0 + col;
      *(short8*)(&Bs[row * LDK + col]) = cvt8(*(const f32x4*)Wp, *(const f32x4*)(Wp + 4));
    }
    __syncthreads();

    short8 af[4], bf[4];
    #pragma unroll
    for (int i = 0; i < 4; ++i)
      af[i] = *(const short8*)(&As[(wm + i * 16 + l16) * LDK + quad * 8]);
    #pragma unroll
    for (int j = 0; j < 4; ++j)
      bf[j] = *(const short8*)(&Bs[(wn + j * 16 + l16) * LDK + quad * 8]);
    #pragma unroll
    for (int i = 0; i < 4; ++i)
      #pragma unroll
      for (int j = 0; j < 4; ++j)
        acc[i][j] = MFMA_BF16_16x16x32(af[i], bf[j], acc[i][j]);
  }

  // C/D layout: col = lane&15, row = quad*4 + reg (m89/m91)
  #pragma unroll
  for (int i = 0; i < 4; ++i)
    #pragma unroll
    for (int j = 0; j < 4; ++j)
      #pragma unroll
      for (int r = 0; r < 4; ++r) {
        int m = m0 + wm + i * 16 + quad * 4 + r;
        int n = n0 + wn + j * 16 + l16;
        unsigned short bv = f2bf(acc[i][j][r] * scale);
        int b = m >> 11, s = m & (S_ - 1);
        int h = n >> 6,  d = n & (DH_ - 1);
        if (epi == 1)
          out[((size_t)(b * H_ + h) * S_ + s) * DH_ + d] = bv;
        else
          out[((size_t)(b * H_ + h) * DH_ + d) * S_ + s] = bv;
      }
}

// ---------------------------------------------------------------------------
// Output projection: C[m][n] = sum_k CTX_bf16[m][k] * Ow_f32[n][k], f32 out.
// ---------------------------------------------------------------------------
__global__ __launch_bounds__(256)
void gemm_out(const unsigned short* __restrict__ A,
              const float* __restrict__ W,
              float* __restrict__ out) {
  constexpr int BM = 128, BK = 32, LDK = 40;
  __shared__ __align__(16) short As[BM * LDK];
  __shared__ __align__(16) short Bs[BM * LDK];

  const int tid  = threadIdx.x;
  const int lane = tid & 63;
  const int w    = tid >> 6;
  const int quad = lane >> 4;
  const int l16  = lane & 15;
  const int wm   = (w >> 1) * 64;
  const int wn   = (w & 1) * 64;

  const int m0 = blockIdx.y * BM;
  const int n0 = blockIdx.x * 128;

  f32x4 acc[4][4];
  #pragma unroll
  for (int i = 0; i < 4; ++i)
    #pragma unroll
    for (int j = 0; j < 4; ++j)
      acc[i][j] = (f32x4){0.f, 0.f, 0.f, 0.f};

  for (int k0 = 0; k0 < D_; k0 += BK) {
    __syncthreads();
    #pragma unroll
    for (int i = 0; i < 2; ++i) {
      int flat = i * 256 + tid;
      int row  = flat >> 2;
      int col  = (flat & 3) * 8;
      *(short8*)(&As[row * LDK + col]) =
          *(const short8*)(A + (size_t)(m0 + row) * D_ + k0 + col);
      const float* Wp = W + (size_t)(n0 + row) * D_ + k0 + col;
      *(short8*)(&Bs[row * LDK + col]) = cvt8(*(const f32x4*)Wp, *(const f32x4*)(Wp + 4));
    }
    __syncthreads();

    short8 af[4], bf[4];
    #pragma unroll
    for (int i = 0; i < 4; ++i)
      af[i] = *(const short8*)(&As[(wm + i * 16 + l16) * LDK + quad * 8]);
    #pragma unroll
    for (int j = 0; j < 4; ++j)
      bf[j] = *(const short8*)(&Bs[(wn + j * 16 + l16) * LDK + quad * 8]);
    #pragma unroll
    for (int i = 0; i < 4; ++i)
      #pragma unroll
      for (int j = 0; j < 4; ++j)
        acc[i][j] = MFMA_BF16_16x16x32(af[i], bf[j], acc[i][j]);
  }

  #pragma unroll
  for (int i = 0; i < 4; ++i)
    #pragma unroll
    for (int j = 0; j < 4; ++j)
      #pragma unroll
      for (int r = 0; r < 4; ++r) {
        int m = m0 + wm + i * 16 + quad * 4 + r;
        int n = n0 + wn + j * 16 + l16;
        out[(size_t)m * D_ + n] = acc[i][j][r];
      }
}

// ---------------------------------------------------------------------------
// MFMA flash attention, single dispatch: grid = (S/128, H, B).
// q-tile order REVERSED (heaviest blocks first -> LPT scheduling; R8 showed
// 11.6% occupancy from the triangular-workload tail).
// Block = 128 q-rows; wave w owns 32 rows (two 16-row subtiles).
// LDS rows padded 64->72 shorts (2-way conflicts only, free per m136).
// ---------------------------------------------------------------------------
__global__ __launch_bounds__(256)
void attn(const unsigned short* __restrict__ Q,    // [B][H,S,DH], pre-scaled 1/8
          const unsigned short* __restrict__ K,    // [B][H,S,DH]
          const unsigned short* __restrict__ VT,   // [B][H,DH,S]
          const unsigned char* __restrict__ pmask, // [B][S] (True = masked)
          unsigned short* __restrict__ CTX) {      // [B][S, H*DH]
  constexpr int LDP = 72;
  __shared__ __align__(16) short Ks[64 * LDP];
  __shared__ __align__(16) short Vs[64 * LDP];
  __shared__ __align__(16) short Ps[4 * 32 * LDP];

  const int tid  = threadIdx.x;
  const int lane = tid & 63;
  const int w    = tid >> 6;
  const int quad = lane >> 4;
  const int l16  = lane & 15;

  const int b  = blockIdx.z;
  const int h  = blockIdx.y;
  const int qt = (gridDim.x - 1) - blockIdx.x;   // reversed q-tile index
  const int q0 = qt * 128;
  const int qw = q0 + w * 32;

  const unsigned short* Qh = Q  + ((size_t)b * H_ + h) * S_ * DH_;
  const unsigned short* Kh = K  + ((size_t)b * H_ + h) * S_ * DH_;
  const unsigned short* Vh = VT + ((size_t)b * H_ + h) * DH_ * S_;
  const unsigned char* pmb = pmask + (size_t)b * S_;
  unsigned short* CTXb = CTX + (size_t)b * S_ * D_;
  short* Pw = &Ps[w * 32 * LDP];

  // Q fragments (A-layout m=lane&15, k=quad*8+j), K-loop invariant
  short8 qf[2][2];
  #pragma unroll
  for (int i = 0; i < 2; ++i)
    #pragma unroll
    for (int c = 0; c < 2; ++c)
      qf[i][c] = *(const short8*)(Qh + (size_t)(qw + i * 16 + l16) * DH_ + c * 32 + quad * 8);

  f32x4 acc[2][4];
  float mrow[2][4], lrow[2][4];
  #pragma unroll
  for (int i = 0; i < 2; ++i)
    #pragma unroll
    for (int t = 0; t < 4; ++t) acc[i][t] = (f32x4){0.f, 0.f, 0.f, 0.f};
  #pragma unroll
  for (int i = 0; i < 2; ++i)
    #pragma unroll
    for (int r = 0; r < 4; ++r) { mrow[i][r] = -1e30f; lrow[i][r] = 0.f; }

  const int ntiles = qt * 2 + 2;   // keys <= q0+127
  for (int kt = 0; kt < ntiles; ++kt) {
    const int k0 = kt * 64;
    __syncthreads();
    #pragma unroll
    for (int i = 0; i < 2; ++i) {
      int flat = i * 256 + tid;
      int r = flat >> 3;
      int c = (flat & 7) * 8;
      *(short8*)(&Ks[r * LDP + c]) = *(const short8*)(Kh + (size_t)(k0 + r) * DH_ + c);
      *(short8*)(&Vs[r * LDP + c]) = *(const short8*)(Vh + (size_t)r * S_ + k0 + c);
    }
    __syncthreads();

    const bool active = (k0 <= qw + 31);
    if (active) {
      f32x4 sc[2][4];
      #pragma unroll
      for (int t = 0; t < 4; ++t) {
        short8 kb0 = *(const short8*)(&Ks[(t * 16 + l16) * LDP + quad * 8]);
        short8 kb1 = *(const short8*)(&Ks[(t * 16 + l16) * LDP + 32 + quad * 8]);
        #pragma unroll
        for (int i = 0; i < 2; ++i) {
          f32x4 z = (f32x4){0.f, 0.f, 0.f, 0.f};
          z = MFMA_BF16_16x16x32(qf[i][0], kb0, z);
          sc[i][t] = MFMA_BF16_16x16x32(qf[i][1], kb1, z);
        }
      }

      #pragma unroll
      for (int t = 0; t < 4; ++t) {
        int key = k0 + t * 16 + l16;
        bool pad = pmb[key] != 0;
        #pragma unroll
        for (int i = 0; i < 2; ++i)
          #pragma unroll
          for (int r = 0; r < 4; ++r) {
            int qrow = qw + i * 16 + quad * 4 + r;
            if (pad || key > qrow) sc[i][t][r] = -1e30f;
          }
      }

      #pragma unroll
      for (int i = 0; i < 2; ++i)
        #pragma unroll
        for (int r = 0; r < 4; ++r) {
          float rm = fmaxf(fmaxf(sc[i][0][r], sc[i][1][r]), fmaxf(sc[i][2][r], sc[i][3][r]));
          #pragma unroll
          for (int off = 8; off; off >>= 1) rm = fmaxf(rm, __shfl_xor(rm, off, 16));
          float mnew = fmaxf(mrow[i][r], rm);
          float al = __expf(mrow[i][r] - mnew);
          float rs = 0.f;
          #pragma unroll
          for (int t = 0; t < 4; ++t) {
            float p = __expf(sc[i][t][r] - mnew);
            sc[i][t][r] = p;
            rs += p;
          }
          #pragma unroll
          for (int off = 8; off; off >>= 1) rs += __shfl_xor(rs, off, 16);
          lrow[i][r] = lrow[i][r] * al + rs;
          mrow[i][r] = mnew;
          #pragma unroll
          for (int t = 0; t < 4; ++t) acc[i][t][r] *= al;
        }

      #pragma unroll
      for (int i = 0; i < 2; ++i)
        #pragma unroll
        for (int t = 0; t < 4; ++t)
          #pragma unroll
          for (int r = 0; r < 4; ++r)
            Pw[(i * 16 + quad * 4 + r) * LDP + t * 16 + l16] = (short)f2bf(sc[i][t][r]);
    }
    __syncthreads();   // order P-store vs vector re-read

    if (active) {
      #pragma unroll
      for (int ks = 0; ks < 2; ++ks) {
        short8 pa0 = *(const short8*)(&Pw[l16 * LDP + ks * 32 + quad * 8]);
        short8 pa1 = *(const short8*)(&Pw[(16 + l16) * LDP + ks * 32 + quad * 8]);
        #pragma unroll
        for (int t = 0; t < 4; ++t) {
          short8 vb = *(const short8*)(&Vs[(t * 16 + l16) * LDP + ks * 32 + quad * 8]);
          acc[0][t] = MFMA_BF16_16x16x32(pa0, vb, acc[0][t]);
          acc[1][t] = MFMA_BF16_16x16x32(pa1, vb, acc[1][t]);
        }
      }
    }
  }

  #pragma unroll
  for (int i = 0; i < 2; ++i)
    #pragma unroll
    for (int r = 0; r < 4; ++r) {
      int qrow = qw + i * 16 + quad * 4 + r;
      float inv = 1.0f / lrow[i][r];
      #pragma unroll
      for (int t = 0; t < 4; ++t)
        CTXb[(size_t)qrow * D_ + h * DH_ + t * 16 + l16] = f2bf(acc[i][t][r] * inv);
    }
}

// ---------------------------------------------------------------------------
// Contract: inputs f32, OUTPUT f32. ws 32 MB (proven R5).
// d_out doubles as staging: Q bf16 [0,16M), CTX bf16 [16M,32M).
// fused-QKV -> attn -> d2d CTX->ws -> final GEMM (reads ws, writes d_out).
// ---------------------------------------------------------------------------
extern "C" void kernel_launch(void* const* d_in, const int* in_sizes, int n_in,
                              void* d_out, int out_size, void* d_ws, size_t ws_size,
                              hipStream_t stream) {
  const float* x  = (const float*)d_in[0];
  const float* Qw = (const float*)d_in[1];
  const float* Kw = (const float*)d_in[2];
  const float* Vw = (const float*)d_in[3];
  const float* Ow = (const float*)d_in[4];
  const unsigned char* pm = (const unsigned char*)d_in[5];

  const size_t NE = (size_t)M_ * D_;
  unsigned short* Qall  = (unsigned short*)d_out;        // 16 MB bf16
  unsigned short* CTXa  = (unsigned short*)d_out + NE;   // 16 MB bf16
  unsigned short* Kall  = (unsigned short*)d_ws;         // 16 MB
  unsigned short* VTall = (unsigned short*)d_ws + NE;    // 16 MB

  gemm_qkv<<<dim3(24, M_ / 128), 256, 0, stream>>>(x, Qw, Kw, Vw,
                                                   Qall, Kall, VTall);

  attn<<<dim3(S_ / 128, H_, B_), 256, 0, stream>>>(Qall, Kall, VTall, pm, CTXa);

  hipMemcpyAsync(d_ws, (const void*)CTXa, NE * sizeof(unsigned short),
                 hipMemcpyDeviceToDevice, stream);

  gemm_out<<<dim3(D_ / 128, M_ / 128), 256, 0, stream>>>((unsigned short*)d_ws,
                                                         Ow, (float*)d_out);
}